// Round 2
// baseline (116.519 us; speedup 1.0000x reference)
//
#include <hip/hip_runtime.h>
#include <hip/hip_bf16.h>

// Grouped linear: concat(x0..x3) rows [M=294912, K=128] @ W^T[128,128] + bias -> fp32 out.
// bf16 MFMA (16x16x32). 512-thread blocks, 256-row chunks, W staged once in swizzled LDS,
// per-wave 2 tiles with all 16 global loads hoisted for memory-level parallelism.

typedef __attribute__((ext_vector_type(8))) short bf8_t;   // 8 x bf16 (4 VGPRs)
typedef __attribute__((ext_vector_type(4))) float f4_t;

__device__ __forceinline__ short bfc(float f) {
    // compiler emits v_cvt_pk_bf16_f32 for pairs (RNE)
    return __builtin_bit_cast(short, __float2bfloat16(f));
}

__device__ __forceinline__ unsigned short f2bf_rne(float f) {
    unsigned u = __builtin_bit_cast(unsigned, f);
    u += 0x7fffu + ((u >> 16) & 1u);
    return (unsigned short)(u >> 16);
}

#define SEG0 131072L   // rows in x0 (32*64*64)
#define SEG1 196608L   // + x1 (32*32*64)
#define SEG2 262144L   // + x2 (32*64*32)
// total 294912 rows; all boundaries divisible by 256 -> a 256-row chunk never straddles

__device__ __forceinline__ void tile_mfma_store(
    const f4_t (&raw)[8], const unsigned short* __restrict__ Wl,
    const float* __restrict__ bl, float* __restrict__ orow,
    int lm, int lk, int nsw)
{
    // convert to bf16 B-fragments: lane holds B[k=lk*8+j][n=lm] = x[row=lm][k]
    bf8_t xf[4];
#pragma unroll
    for (int ks = 0; ks < 4; ++ks) {
        bf8_t t;
        t[0] = bfc(raw[2 * ks].x);
        t[1] = bfc(raw[2 * ks].y);
        t[2] = bfc(raw[2 * ks].z);
        t[3] = bfc(raw[2 * ks].w);
        t[4] = bfc(raw[2 * ks + 1].x);
        t[5] = bfc(raw[2 * ks + 1].y);
        t[6] = bfc(raw[2 * ks + 1].z);
        t[7] = bfc(raw[2 * ks + 1].w);
        xf[ks] = t;
    }

    // acc[nt] holds out[row=lm][col = nt*16 + lk*4 + j]; init from bias
    f4_t acc[8];
#pragma unroll
    for (int nt = 0; nt < 8; ++nt)
        acc[nt] = *reinterpret_cast<const f4_t*>(&bl[nt * 16 + lk * 4]);

    // swapped-operand MFMA: A = W tile (16 out-cols x 32 k), B = x^T
#pragma unroll
    for (int nt = 0; nt < 8; ++nt) {
        const int nrow = nt * 16 + lm;
#pragma unroll
        for (int ks = 0; ks < 4; ++ks) {
            const int c = (ks * 4 + lk) ^ nsw;  // swizzled 16B chunk
            bf8_t wf = *reinterpret_cast<const bf8_t*>(&Wl[nrow * 128 + c * 8]);
            acc[nt] = __builtin_amdgcn_mfma_f32_16x16x32_bf16(wf, xf[ks], acc[nt], 0, 0, 0);
        }
    }

    // coalesced f32x4 stores: lane writes 4 consecutive cols of its row
#pragma unroll
    for (int nt = 0; nt < 8; ++nt)
        *reinterpret_cast<f4_t*>(orow + nt * 16 + lk * 4) = acc[nt];
}

__global__ __launch_bounds__(512, 4)
void lin_kernel(const float* __restrict__ x0, const float* __restrict__ x1,
                const float* __restrict__ x2, const float* __restrict__ x3,
                const float* __restrict__ W, const float* __restrict__ bias,
                float* __restrict__ out)
{
    __shared__ unsigned short Wl[128 * 128]; // bf16 W, 256B rows, 16B-chunk XOR swizzle
    __shared__ float bl[128];

    const int tid = threadIdx.x;

    // ---- stage W: fp32 -> bf16, swizzled (chunk ^= row&7 breaks the 16-way bank conflict) ----
#pragma unroll
    for (int i = 0; i < 8; ++i) {
        int f  = i * 512 + tid;       // float4 index in W, 0..4095
        int n  = f >> 5;              // W row (output feature)
        int k4 = f & 31;              // float4 index within row
        f4_t v = reinterpret_cast<const f4_t*>(W)[f];
        unsigned long long p =
              (unsigned long long)f2bf_rne(v.x)
            | ((unsigned long long)f2bf_rne(v.y) << 16)
            | ((unsigned long long)f2bf_rne(v.z) << 32)
            | ((unsigned long long)f2bf_rne(v.w) << 48);
        int sc = (k4 >> 1) ^ (n & 7); // swizzled 16B-chunk index
        *reinterpret_cast<unsigned long long*>(&Wl[n * 128 + sc * 8 + (k4 & 1) * 4]) = p;
    }
    if (tid < 128) bl[tid] = bias[tid];
    __syncthreads();

    const int wave = tid >> 6;
    const int lane = tid & 63;
    const int lm   = lane & 15;   // x-row-within-tile
    const int lk   = lane >> 4;   // 0..3 (k-group)
    const int nsw  = lm & 7;      // swizzle key for W reads

    const long base = (long)blockIdx.x * 256;   // 256-row chunk
    const float* xp; long loc;
    if      (base < SEG0) { xp = x0; loc = base; }
    else if (base < SEG1) { xp = x1; loc = base - SEG0; }
    else if (base < SEG2) { xp = x2; loc = base - SEG1; }
    else                  { xp = x3; loc = base - SEG2; }

    const int r = wave * 16 + lm;               // tile-A row within chunk (tile B = +128)
    const float* pA = xp + (loc + r) * 128;
    const float* pB = pA + 128 * 128;

    // ---- hoist ALL 16 loads (both tiles) for memory-level parallelism ----
    f4_t rawA[8], rawB[8];
#pragma unroll
    for (int ks = 0; ks < 4; ++ks) {
        const float* p = pA + ks * 32 + lk * 8;
        rawA[2 * ks]     = *reinterpret_cast<const f4_t*>(p);
        rawA[2 * ks + 1] = *reinterpret_cast<const f4_t*>(p + 4);
    }
#pragma unroll
    for (int ks = 0; ks < 4; ++ks) {
        const float* p = pB + ks * 32 + lk * 8;
        rawB[2 * ks]     = *reinterpret_cast<const f4_t*>(p);
        rawB[2 * ks + 1] = *reinterpret_cast<const f4_t*>(p + 4);
    }

    float* oA = out + (base + r) * 128;
    float* oB = oA + 128 * 128;

    tile_mfma_store(rawA, Wl, bl, oA, lm, lk, nsw);
    tile_mfma_store(rawB, Wl, bl, oB, lm, lk, nsw);
}

extern "C" void kernel_launch(void* const* d_in, const int* in_sizes, int n_in,
                              void* d_out, int out_size, void* d_ws, size_t ws_size,
                              hipStream_t stream) {
    const float* x0 = (const float*)d_in[0];
    const float* x1 = (const float*)d_in[1];
    const float* x2 = (const float*)d_in[2];
    const float* x3 = (const float*)d_in[3];
    const float* W  = (const float*)d_in[4];
    const float* b  = (const float*)d_in[5];
    float* out = (float*)d_out;

    // 294912 rows / 256 rows per block = 1152 blocks
    hipLaunchKernelGGL(lin_kernel, dim3(1152), dim3(512), 0, stream,
                       x0, x1, x2, x3, W, b, out);
}

// Round 3
// 59.794 us; speedup vs baseline: 1.9487x; 1.9487x over previous
//
#include <hip/hip_runtime.h>
#include <hip/hip_bf16.h>

// Grouped linear: concat(x0..x3) rows [M=294912, K=128] @ W^T[128,128] + bias -> fp32 out.
// bf16 MFMA (16x16x32). 256-thread blocks, 256-row chunks, W staged once in swizzled LDS.
// 2-deep software pipeline (load tile t+1 while computing tile t), VGPR-budgeted.
// Non-temporal output stores to keep x L3-resident.

typedef __attribute__((ext_vector_type(8))) short bf8_t;   // 8 x bf16 (4 VGPRs)
typedef __attribute__((ext_vector_type(4))) float f4_t;

__device__ __forceinline__ short bfc(float f) {
    // compiler pairs these into v_cvt_pk_bf16_f32 (RNE)
    return __builtin_bit_cast(short, __float2bfloat16(f));
}

__device__ __forceinline__ unsigned short f2bf_rne(float f) {
    unsigned u = __builtin_bit_cast(unsigned, f);
    u += 0x7fffu + ((u >> 16) & 1u);
    return (unsigned short)(u >> 16);
}

#define SEG0 131072L   // rows in x0 (32*64*64)
#define SEG1 196608L   // + x1 (32*32*64)
#define SEG2 262144L   // + x2 (32*64*32)
// total 294912 rows; all boundaries divisible by 256 -> a 256-row chunk never straddles

__device__ __forceinline__ void load_tile(f4_t (&raw)[8], const float* __restrict__ rowbase, int lk)
{
#pragma unroll
    for (int ks = 0; ks < 4; ++ks) {
        const float* p = rowbase + ks * 32 + lk * 8;
        raw[2 * ks]     = *reinterpret_cast<const f4_t*>(p);
        raw[2 * ks + 1] = *reinterpret_cast<const f4_t*>(p + 4);
    }
}

__device__ __forceinline__ void compute_store(
    const f4_t (&raw)[8], const unsigned short* __restrict__ Wl,
    const float* __restrict__ bl, float* __restrict__ orow,
    int lm, int lk, int nsw)
{
    // bf16 B-fragments: lane holds B[k=lk*8+j][n=lm] = x[row=lm][k]
    bf8_t xf[4];
#pragma unroll
    for (int ks = 0; ks < 4; ++ks) {
        bf8_t t;
        t[0] = bfc(raw[2 * ks].x);
        t[1] = bfc(raw[2 * ks].y);
        t[2] = bfc(raw[2 * ks].z);
        t[3] = bfc(raw[2 * ks].w);
        t[4] = bfc(raw[2 * ks + 1].x);
        t[5] = bfc(raw[2 * ks + 1].y);
        t[6] = bfc(raw[2 * ks + 1].z);
        t[7] = bfc(raw[2 * ks + 1].w);
        xf[ks] = t;
    }

    // acc[nt] = out[row=lm][col = nt*16 + lk*4 + j]; init from bias
    f4_t acc[8];
#pragma unroll
    for (int nt = 0; nt < 8; ++nt)
        acc[nt] = *reinterpret_cast<const f4_t*>(&bl[nt * 16 + lk * 4]);

    // swapped-operand MFMA: A = W tile (16 out-cols x 32 k), B = x^T
#pragma unroll
    for (int nt = 0; nt < 8; ++nt) {
        const int nrow = nt * 16 + lm;
#pragma unroll
        for (int ks = 0; ks < 4; ++ks) {
            const int c = (ks * 4 + lk) ^ nsw;  // swizzled 16B chunk
            bf8_t wf = *reinterpret_cast<const bf8_t*>(&Wl[nrow * 128 + c * 8]);
            acc[nt] = __builtin_amdgcn_mfma_f32_16x16x32_bf16(wf, xf[ks], acc[nt], 0, 0, 0);
        }
    }

    // streaming f32x4 stores (non-temporal: out is never re-read; keep x in L3)
#pragma unroll
    for (int nt = 0; nt < 8; ++nt)
        __builtin_nontemporal_store(acc[nt], reinterpret_cast<f4_t*>(orow + nt * 16 + lk * 4));
}

__global__ __launch_bounds__(256)
void lin_kernel(const float* __restrict__ x0, const float* __restrict__ x1,
                const float* __restrict__ x2, const float* __restrict__ x3,
                const float* __restrict__ W, const float* __restrict__ bias,
                float* __restrict__ out)
{
    __shared__ unsigned short Wl[128 * 128]; // bf16 W, 256B rows, 16B-chunk XOR swizzle
    __shared__ float bl[128];

    const int tid = threadIdx.x;

    // ---- stage W: fp32 -> bf16, swizzled (chunk ^= row&7 breaks the 16-way bank conflict) ----
#pragma unroll
    for (int i = 0; i < 16; ++i) {
        int f  = i * 256 + tid;       // float4 index in W, 0..4095
        int n  = f >> 5;              // W row (output feature)
        int k4 = f & 31;              // float4 index within row
        f4_t v = reinterpret_cast<const f4_t*>(W)[f];
        unsigned long long p =
              (unsigned long long)f2bf_rne(v.x)
            | ((unsigned long long)f2bf_rne(v.y) << 16)
            | ((unsigned long long)f2bf_rne(v.z) << 32)
            | ((unsigned long long)f2bf_rne(v.w) << 48);
        int sc = (k4 >> 1) ^ (n & 7); // swizzled 16B-chunk index
        *reinterpret_cast<unsigned long long*>(&Wl[n * 128 + sc * 8 + (k4 & 1) * 4]) = p;
    }
    if (tid < 128) bl[tid] = bias[tid];
    __syncthreads();

    const int wave = tid >> 6;
    const int lane = tid & 63;
    const int lm   = lane & 15;   // x-row-within-tile
    const int lk   = lane >> 4;   // 0..3 (k-group)
    const int nsw  = lm & 7;      // swizzle key for W reads

    const long base = (long)blockIdx.x * 256;   // 256-row chunk
    const float* xp; long loc;
    if      (base < SEG0) { xp = x0; loc = base; }
    else if (base < SEG1) { xp = x1; loc = base - SEG0; }
    else if (base < SEG2) { xp = x2; loc = base - SEG1; }
    else                  { xp = x3; loc = base - SEG2; }

    const int  rw    = wave * 16 + lm;          // row-in-chunk for tile t: t*64 + rw
    const float* xb  = xp + (loc + rw) * 128;   // tile t row base: xb + t*64*128
    float*       ob  = out + (base + rw) * 128; // tile t out base: ob + t*64*128

    // ---- 2-deep pipeline over 4 tiles (fully unrolled, static buffers, ~120 VGPR) ----
    f4_t rawA[8], rawB[8];
    load_tile(rawA, xb,             lk);
    load_tile(rawB, xb + 1 * 8192,  lk);
    compute_store(rawA, Wl, bl, ob,            lm, lk, nsw);
    load_tile(rawA, xb + 2 * 8192,  lk);
    compute_store(rawB, Wl, bl, ob + 1 * 8192, lm, lk, nsw);
    load_tile(rawB, xb + 3 * 8192,  lk);
    compute_store(rawA, Wl, bl, ob + 2 * 8192, lm, lk, nsw);
    compute_store(rawB, Wl, bl, ob + 3 * 8192, lm, lk, nsw);
}

extern "C" void kernel_launch(void* const* d_in, const int* in_sizes, int n_in,
                              void* d_out, int out_size, void* d_ws, size_t ws_size,
                              hipStream_t stream) {
    const float* x0 = (const float*)d_in[0];
    const float* x1 = (const float*)d_in[1];
    const float* x2 = (const float*)d_in[2];
    const float* x3 = (const float*)d_in[3];
    const float* W  = (const float*)d_in[4];
    const float* b  = (const float*)d_in[5];
    float* out = (float*)d_out;

    // 294912 rows / 256 rows per block = 1152 blocks
    hipLaunchKernelGGL(lin_kernel, dim3(1152), dim3(256), 0, stream,
                       x0, x1, x2, x3, W, b, out);
}